// Round 9
// baseline (569.733 us; speedup 1.0000x reference)
//
#include <hip/hip_runtime.h>
#include <hip/hip_fp16.h>

#define FDIM 128
#define NCLS 16

#define SCAN_T 256
#define SCAN_I 8
#define SCAN_CHUNK (SCAN_T * SCAN_I)  // 2048 elements per block

// ---------------- CSR build ----------------
__global__ void k_zero_cnt(int* cnt, int n) {
    int i = blockIdx.x * blockDim.x + threadIdx.x;
    if (i < n) cnt[i] = 0;
}

__global__ void k_count(const int* __restrict__ dst, int* cnt, int e) {
    int i = blockIdx.x * blockDim.x + threadIdx.x;
    if (i < e) atomicAdd(&cnt[dst[i]], 1);
}

// phase 1: block-local exclusive scan, per-block total; also computes dinv
__global__ __launch_bounds__(SCAN_T) void k_scan1(const int* __restrict__ cnt,
                                                  int* __restrict__ excl,
                                                  int* __restrict__ blockSum,
                                                  float* __restrict__ dinv, int n) {
    __shared__ int ts[SCAN_T];
    int b = blockIdx.x, t = threadIdx.x;
    int base = b * SCAN_CHUNK + t * SCAN_I;
    int v[SCAN_I];
    int s = 0;
    #pragma unroll
    for (int i = 0; i < SCAN_I; ++i) {
        int idx = base + i;
        v[i] = (idx < n) ? cnt[idx] : 0;
        if (idx < n) dinv[idx] = rsqrtf((float)(v[i] + 1));  // +1 self-loop
        s += v[i];
    }
    ts[t] = s;
    __syncthreads();
    for (int off = 1; off < SCAN_T; off <<= 1) {
        int x = (t >= off) ? ts[t - off] : 0;
        __syncthreads();
        ts[t] += x;
        __syncthreads();
    }
    int ex = (t == 0) ? 0 : ts[t - 1];
    #pragma unroll
    for (int i = 0; i < SCAN_I; ++i) {
        int idx = base + i;
        if (idx < n) excl[idx] = ex;
        ex += v[i];
    }
    if (t == SCAN_T - 1) blockSum[b] = ts[SCAN_T - 1];
}

// phase 2: single block exclusive-scans the block totals (nb <= 1024)
__global__ __launch_bounds__(1024) void k_scan2(int* blockSum, int* total, int nb) {
    __shared__ int ts[1024];
    int t = threadIdx.x;
    int v = (t < nb) ? blockSum[t] : 0;
    ts[t] = v;
    __syncthreads();
    for (int off = 1; off < 1024; off <<= 1) {
        int x = (t >= off) ? ts[t - off] : 0;
        __syncthreads();
        ts[t] += x;
        __syncthreads();
    }
    if (t < nb) blockSum[t] = (t == 0) ? 0 : ts[t - 1];
    if (t == 1023) *total = ts[1023];
}

// phase 3: add block offsets, copy to cursor, write row_ptr[n]
__global__ void k_scan3(int* __restrict__ row_ptr, int* __restrict__ cursor,
                        const int* __restrict__ blockSum, const int* __restrict__ total,
                        int n) {
    int i = blockIdx.x * blockDim.x + threadIdx.x;
    if (i < n) {
        int v = row_ptr[i] + blockSum[i / SCAN_CHUNK];
        row_ptr[i] = v;
        cursor[i] = v;
    }
    if (i == 0) row_ptr[n] = *total;
}

// scatter: store BYTE offset of the fp16 source row (src * 256)
__global__ void k_scatter(const int* __restrict__ src, const int* __restrict__ dst,
                          int* cursor, int* __restrict__ csr_off, int e) {
    int i = blockIdx.x * blockDim.x + threadIdx.x;
    if (i >= e) return;
    int pos = atomicAdd(&cursor[dst[i]], 1);
    csr_off[pos] = src[i] << 8;  // fp16 row stride = 128*2 = 256 B
}

// ------- GEMM: Y[n,128](fp16) = (A[n,128] @ W[128,128]) * dinv[row] -------
// 512 threads, 128x128 tile, 8 rows x 4 cols per thread; A fp32 or fp16
#define GT 512
#define GR 128
template <typename T>
__global__ __launch_bounds__(GT) void k_gemm128(const T* __restrict__ A,
                                                const float* __restrict__ W,
                                                const float* __restrict__ dinv,
                                                __half* __restrict__ C, int n) {
    __shared__ float ws[128 * 128];   // [k][c], 64 KB
    __shared__ float xs[GR * 132];    // [r][k] padded to 132
    int t = threadIdx.x;
    const float4* W4 = reinterpret_cast<const float4*>(W);
    #pragma unroll
    for (int i = t; i < 128 * 32; i += GT)
        reinterpret_cast<float4*>(ws)[i] = W4[i];

    int row0 = blockIdx.x * GR;
    if constexpr (sizeof(T) == 4) {
        for (int i = t; i < GR * 32; i += GT) {
            int r = i >> 5, k4 = i & 31;
            float4 v = (row0 + r < n)
                ? reinterpret_cast<const float4*>(A)[(size_t)(row0 + r) * 32 + k4]
                : make_float4(0.f, 0.f, 0.f, 0.f);
            *reinterpret_cast<float4*>(&xs[r * 132 + k4 * 4]) = v;
        }
    } else {
        // fp16 input: 8 halves (16B) per iteration
        for (int i = t; i < GR * 16; i += GT) {
            int r = i >> 4, c8 = i & 15;
            uint4 u = make_uint4(0, 0, 0, 0);
            if (row0 + r < n)
                u = reinterpret_cast<const uint4*>(A)[(size_t)(row0 + r) * 16 + c8];
            const __half2* hp = reinterpret_cast<const __half2*>(&u);
            float2 f0 = __half22float2(hp[0]);
            float2 f1 = __half22float2(hp[1]);
            float2 f2 = __half22float2(hp[2]);
            float2 f3 = __half22float2(hp[3]);
            float* d = &xs[r * 132 + c8 * 8];
            *reinterpret_cast<float4*>(d)     = make_float4(f0.x, f0.y, f1.x, f1.y);
            *reinterpret_cast<float4*>(d + 4) = make_float4(f2.x, f2.y, f3.x, f3.y);
        }
    }
    __syncthreads();

    int tc = t & 31, tr = t >> 5;   // tr 0..15
    int c0 = tc * 4, r0 = tr * 8;
    float4 acc[8] = {};
    for (int k = 0; k < 128; k += 4) {
        float4 a[8];
        #pragma unroll
        for (int i = 0; i < 8; ++i)
            a[i] = *reinterpret_cast<const float4*>(&xs[(r0 + i) * 132 + k]);
        #pragma unroll
        for (int kk = 0; kk < 4; ++kk) {
            float4 w4 = *reinterpret_cast<const float4*>(&ws[(k + kk) * 128 + c0]);
            #pragma unroll
            for (int i = 0; i < 8; ++i) {
                float av = (kk == 0) ? a[i].x : (kk == 1) ? a[i].y : (kk == 2) ? a[i].z : a[i].w;
                acc[i].x += av * w4.x;
                acc[i].y += av * w4.y;
                acc[i].z += av * w4.z;
                acc[i].w += av * w4.w;
            }
        }
    }
    #pragma unroll
    for (int i = 0; i < 8; ++i) {
        int r = row0 + r0 + i;
        if (r < n) {
            float s = dinv[r];
            __half2 h0 = __float22half2_rn(make_float2(acc[i].x * s, acc[i].y * s));
            __half2 h1 = __float22half2_rn(make_float2(acc[i].z * s, acc[i].w * s));
            uint2 pack;
            pack.x = *reinterpret_cast<unsigned int*>(&h0);
            pack.y = *reinterpret_cast<unsigned int*>(&h1);
            reinterpret_cast<uint2*>(C)[(size_t)r * 32 + tc] = pack;  // 8B at col c0
        }
    }
}

// ---------------- aggregation (+ optional fused classifier/softmax) ----------------
// one wave per node; 64 lanes x half2 cover the 128-dim fp16 row. Edge offsets
// (byte offsets, src*256) arrive via ONE coalesced load per 64 edges, then are
// broadcast with v_readlane into SGPRs -> each gather is [sgpr_base + lane*4],
// ~1 VALU per edge. 16 loads in flight per wave; fp16 depth-3 trees, f32 fold
// every 8 edges (numerically identical to R8).
template <bool FUSE>
__global__ __launch_bounds__(256) void k_agg(const __half* __restrict__ Y,
                                             const int* __restrict__ csr_off,
                                             const int* __restrict__ row_ptr,
                                             const float* __restrict__ dinv,
                                             const float* __restrict__ bias,
                                             const float* __restrict__ Wl,
                                             const float* __restrict__ bl,
                                             __half* __restrict__ hout,
                                             float* __restrict__ out, int n) {
    __shared__ float s_wl[NCLS * FDIM];  // transposed: [c][k]
    __shared__ float s_bl[NCLS];
    if (FUSE) {
        for (int i = threadIdx.x; i < FDIM * NCLS / 4; i += 256) {
            int k = i >> 2, c4 = (i & 3) * 4;
            float4 v = reinterpret_cast<const float4*>(Wl)[i];
            s_wl[(c4 + 0) * FDIM + k] = v.x;
            s_wl[(c4 + 1) * FDIM + k] = v.y;
            s_wl[(c4 + 2) * FDIM + k] = v.z;
            s_wl[(c4 + 3) * FDIM + k] = v.w;
        }
        if (threadIdx.x < NCLS) s_bl[threadIdx.x] = bl[threadIdx.x];
        __syncthreads();
    }

    int node = blockIdx.x * 4 + (threadIdx.x >> 6);
    if (node >= n) return;
    int lane = threadIdx.x & 63;
    int lb = lane << 2;  // byte offset of this lane's half2 within a 256B row

    const char* Yb = reinterpret_cast<const char*>(Y);
    float2 acc = __half22float2(
        *reinterpret_cast<const __half2*>(Yb + ((size_t)node << 8) + lb));  // self
    int beg = row_ptr[node], end = row_ptr[node + 1];

    for (int j0 = beg; j0 < end; j0 += 64) {
        int cnt = min(64, end - j0);
        int myoff = (j0 + lane < end) ? csr_off[j0 + lane] : 0;
        int k = 0;
        for (; k + 16 <= cnt; k += 16) {
            __half2 v[16];
            #pragma unroll
            for (int i = 0; i < 16; ++i) {
                int o = __builtin_amdgcn_readlane(myoff, k + i);
                v[i] = *reinterpret_cast<const __half2*>(Yb + o + lb);
            }
            // two depth-3 fp16 trees, fold to f32 (same numerics as R8)
            __half2 a0 = __hadd2(__hadd2(__hadd2(v[0], v[1]), __hadd2(v[2], v[3])),
                                 __hadd2(__hadd2(v[4], v[5]), __hadd2(v[6], v[7])));
            __half2 a1 = __hadd2(__hadd2(__hadd2(v[8], v[9]), __hadd2(v[10], v[11])),
                                 __hadd2(__hadd2(v[12], v[13]), __hadd2(v[14], v[15])));
            float2 f0 = __half22float2(a0);
            float2 f1 = __half22float2(a1);
            acc.x += f0.x + f1.x;
            acc.y += f0.y + f1.y;
        }
        for (; k + 8 <= cnt; k += 8) {
            __half2 v[8];
            #pragma unroll
            for (int i = 0; i < 8; ++i) {
                int o = __builtin_amdgcn_readlane(myoff, k + i);
                v[i] = *reinterpret_cast<const __half2*>(Yb + o + lb);
            }
            __half2 a0 = __hadd2(__hadd2(__hadd2(v[0], v[1]), __hadd2(v[2], v[3])),
                                 __hadd2(__hadd2(v[4], v[5]), __hadd2(v[6], v[7])));
            float2 f0 = __half22float2(a0);
            acc.x += f0.x;
            acc.y += f0.y;
        }
        for (; k < cnt; ++k) {
            int o = __builtin_amdgcn_readlane(myoff, k);
            float2 f = __half22float2(*reinterpret_cast<const __half2*>(Yb + o + lb));
            acc.x += f.x;
            acc.y += f.y;
        }
    }

    float di = dinv[node];
    float2 b = reinterpret_cast<const float2*>(bias)[lane];
    float hx = fmaxf(acc.x * di + b.x, 0.f);
    float hy = fmaxf(acc.y * di + b.y, 0.f);

    if (!FUSE) {
        reinterpret_cast<__half2*>(hout)[(size_t)node * 64 + lane] =
            __float22half2_rn(make_float2(hx, hy));
    } else {
        float lg[NCLS];
        #pragma unroll
        for (int c = 0; c < NCLS; ++c) {
            float2 w2 = *reinterpret_cast<const float2*>(&s_wl[c * FDIM + lane * 2]);
            lg[c] = hx * w2.x + hy * w2.y;
        }
        #pragma unroll
        for (int off = 1; off < 64; off <<= 1) {
            #pragma unroll
            for (int c = 0; c < NCLS; ++c) lg[c] += __shfl_xor(lg[c], off, 64);
        }
        #pragma unroll
        for (int c = 0; c < NCLS; ++c) lg[c] += s_bl[c];
        float m = lg[0];
        #pragma unroll
        for (int c = 1; c < NCLS; ++c) m = fmaxf(m, lg[c]);
        float ev[NCLS];
        float sum = 0.f;
        #pragma unroll
        for (int c = 0; c < NCLS; ++c) { ev[c] = __expf(lg[c] - m); sum += ev[c]; }
        float inv = 1.0f / sum;
        float mye = 0.f;
        #pragma unroll
        for (int c = 0; c < NCLS; ++c) if (lane == c) mye = ev[c];  // static idx
        if (lane < NCLS) out[(size_t)node * NCLS + lane] = mye * inv;
    }
}

extern "C" void kernel_launch(void* const* d_in, const int* in_sizes, int n_in,
                              void* d_out, int out_size, void* d_ws, size_t ws_size,
                              hipStream_t stream) {
    const float* x  = (const float*)d_in[0];
    const int*   ei = (const int*)d_in[1];
    const float* W1 = (const float*)d_in[2];
    const float* b1 = (const float*)d_in[3];
    const float* W2 = (const float*)d_in[4];
    const float* b2 = (const float*)d_in[5];
    const float* Wl = (const float*)d_in[6];
    const float* bl = (const float*)d_in[7];
    float* out = (float*)d_out;

    int n = in_sizes[0] / FDIM;
    int e = in_sizes[1] / 2;
    const int* src = ei;
    const int* dst = ei + e;

    int nb = (n + SCAN_CHUNK - 1) / SCAN_CHUNK;  // <=1024

    // workspace layout
    float* dinv    = (float*)d_ws;                     // n
    int*   cnt     = (int*)(dinv + n);                 // n
    int*   row_ptr = cnt + n;                          // n+1
    int*   cursor  = row_ptr + n + 1;                  // n
    int*   blockSum= cursor + n;                       // nb (<=1024)
    int*   total   = blockSum + 1024;                  // 1
    int*   csr_off = total + 1;                        // e
    uintptr_t p = (uintptr_t)(csr_off + e);
    p = (p + 15) & ~(uintptr_t)15;
    __half* bufA = (__half*)p;                         // n*128 halves
    __half* bufB = bufA + (size_t)n * FDIM;            // n*128 halves

    int bn = (n + 255) / 256;
    int be = (e + 255) / 256;

    // CSR + norms
    k_zero_cnt<<<bn, 256, 0, stream>>>(cnt, n);
    k_count<<<be, 256, 0, stream>>>(dst, cnt, e);
    k_scan1<<<nb, SCAN_T, 0, stream>>>(cnt, row_ptr, blockSum, dinv, n);
    k_scan2<<<1, 1024, 0, stream>>>(blockSum, total, nb);
    k_scan3<<<bn, 256, 0, stream>>>(row_ptr, cursor, blockSum, total, n);
    k_scatter<<<be, 256, 0, stream>>>(src, dst, cursor, csr_off, e);

    int bg = (n + GR - 1) / GR;
    int ba = (n + 3) / 4;

    // layer 1
    k_gemm128<float><<<bg, GT, 0, stream>>>(x, W1, dinv, bufA, n);
    k_agg<false><<<ba, 256, 0, stream>>>(bufA, csr_off, row_ptr, dinv, b1, Wl, bl, bufB, out, n);

    // layer 2 (+ fused classifier/softmax)
    k_gemm128<__half><<<bg, GT, 0, stream>>>(bufB, W2, dinv, bufA, n);
    k_agg<true><<<ba, 256, 0, stream>>>(bufA, csr_off, row_ptr, dinv, b2, Wl, bl, bufB, out, n);
}

// Round 10
// 509.333 us; speedup vs baseline: 1.1186x; 1.1186x over previous
//
#include <hip/hip_runtime.h>
#include <hip/hip_fp16.h>

#define FDIM 128
#define NCLS 16

#define SCAN_T 256
#define SCAN_I 8
#define SCAN_CHUNK (SCAN_T * SCAN_I)  // 2048 elements per block

typedef _Float16 f16x8 __attribute__((ext_vector_type(8)));
typedef float f32x4 __attribute__((ext_vector_type(4)));

// ---------------- CSR build ----------------
__global__ void k_count(const int* __restrict__ dst, int* cnt, int e) {
    int i = blockIdx.x * blockDim.x + threadIdx.x;
    if (i < e) atomicAdd(&cnt[dst[i]], 1);
}

// phase 1: block-local exclusive scan, per-block total; also computes dinv
__global__ __launch_bounds__(SCAN_T) void k_scan1(const int* __restrict__ cnt,
                                                  int* __restrict__ excl,
                                                  int* __restrict__ blockSum,
                                                  float* __restrict__ dinv, int n) {
    __shared__ int ts[SCAN_T];
    int b = blockIdx.x, t = threadIdx.x;
    int base = b * SCAN_CHUNK + t * SCAN_I;
    int v[SCAN_I];
    int s = 0;
    #pragma unroll
    for (int i = 0; i < SCAN_I; ++i) {
        int idx = base + i;
        v[i] = (idx < n) ? cnt[idx] : 0;
        if (idx < n) dinv[idx] = rsqrtf((float)(v[i] + 1));  // +1 self-loop
        s += v[i];
    }
    ts[t] = s;
    __syncthreads();
    for (int off = 1; off < SCAN_T; off <<= 1) {
        int x = (t >= off) ? ts[t - off] : 0;
        __syncthreads();
        ts[t] += x;
        __syncthreads();
    }
    int ex = (t == 0) ? 0 : ts[t - 1];
    #pragma unroll
    for (int i = 0; i < SCAN_I; ++i) {
        int idx = base + i;
        if (idx < n) excl[idx] = ex;
        ex += v[i];
    }
    if (t == SCAN_T - 1) blockSum[b] = ts[SCAN_T - 1];
}

// phase 2: single block exclusive-scans the block totals (nb <= 1024)
__global__ __launch_bounds__(1024) void k_scan2(int* blockSum, int* total, int nb) {
    __shared__ int ts[1024];
    int t = threadIdx.x;
    int v = (t < nb) ? blockSum[t] : 0;
    ts[t] = v;
    __syncthreads();
    for (int off = 1; off < 1024; off <<= 1) {
        int x = (t >= off) ? ts[t - off] : 0;
        __syncthreads();
        ts[t] += x;
        __syncthreads();
    }
    if (t < nb) blockSum[t] = (t == 0) ? 0 : ts[t - 1];
    if (t == 1023) *total = ts[1023];
}

// phase 3: add block offsets, copy to cursor, write row_ptr[n]
__global__ void k_scan3(int* __restrict__ row_ptr, int* __restrict__ cursor,
                        const int* __restrict__ blockSum, const int* __restrict__ total,
                        int n) {
    int i = blockIdx.x * blockDim.x + threadIdx.x;
    if (i < n) {
        int v = row_ptr[i] + blockSum[i / SCAN_CHUNK];
        row_ptr[i] = v;
        cursor[i] = v;
    }
    if (i == 0) row_ptr[n] = *total;
}

// scatter: store BYTE offset of the fp16 source row (src * 256)
__global__ void k_scatter(const int* __restrict__ src, const int* __restrict__ dst,
                          int* cursor, int* __restrict__ csr_off, int e) {
    int i = blockIdx.x * blockDim.x + threadIdx.x;
    if (i >= e) return;
    int pos = atomicAdd(&cursor[dst[i]], 1);
    csr_off[pos] = src[i] << 8;  // fp16 row stride = 128*2 = 256 B
}

// ------- MFMA GEMM: Y[n,128](fp16) = (A[n,128] @ W[128,128]) * dinv[row] -------
// 256 threads = 4 waves; 64 rows x 128 cols per block; v_mfma_f32_16x16x32_f16.
// A and W^T staged in LDS as fp16 with XOR swizzle (byte ^= (row&7)<<4) so
// fragment ds_read_b128 are conflict-light (G4).
template <typename T>
__global__ __launch_bounds__(256) void k_gemm_mfma(const T* __restrict__ A,
                                                   const float* __restrict__ W,
                                                   const float* __restrict__ dinv,
                                                   __half* __restrict__ C, int n) {
    __shared__ _Float16 as[64 * 128];    // 16 KB  [r][k] swizzled
    __shared__ _Float16 wt[128 * 128];   // 32 KB  [c][k] swizzled (W transposed)
    int t = threadIdx.x;
    int r0 = blockIdx.x * 64;

    // stage W^T (fp32 -> fp16), scalar transpose writes (once per block, L2-hit reads)
    for (int i = t; i < 128 * 32; i += 256) {
        int k = i >> 5, c4 = (i & 31) * 4;
        float4 w4 = reinterpret_cast<const float4*>(W)[i];  // W[k][c4..c4+3]
        #pragma unroll
        for (int j = 0; j < 4; ++j) {
            int c = c4 + j;
            float wv = (j == 0) ? w4.x : (j == 1) ? w4.y : (j == 2) ? w4.z : w4.w;
            int byte = (c * 256 + k * 2) ^ ((c & 7) << 4);
            wt[byte >> 1] = (_Float16)wv;
        }
    }

    // stage A rows r0..r0+63 (cast to fp16 if fp32 input), 16B chunks
    if constexpr (sizeof(T) == 4) {
        for (int i = t; i < 64 * 16; i += 256) {
            int r = i >> 4, c8 = i & 15;
            float4 v0 = make_float4(0.f, 0.f, 0.f, 0.f);
            float4 v1 = make_float4(0.f, 0.f, 0.f, 0.f);
            if (r0 + r < n) {
                v0 = reinterpret_cast<const float4*>(A)[(size_t)(r0 + r) * 32 + c8 * 2];
                v1 = reinterpret_cast<const float4*>(A)[(size_t)(r0 + r) * 32 + c8 * 2 + 1];
            }
            __half2 h0 = __float22half2_rn(make_float2(v0.x, v0.y));
            __half2 h1 = __float22half2_rn(make_float2(v0.z, v0.w));
            __half2 h2 = __float22half2_rn(make_float2(v1.x, v1.y));
            __half2 h3 = __float22half2_rn(make_float2(v1.z, v1.w));
            uint4 u;
            u.x = *reinterpret_cast<unsigned int*>(&h0);
            u.y = *reinterpret_cast<unsigned int*>(&h1);
            u.z = *reinterpret_cast<unsigned int*>(&h2);
            u.w = *reinterpret_cast<unsigned int*>(&h3);
            int byte = (r * 256 + c8 * 16) ^ ((r & 7) << 4);
            *reinterpret_cast<uint4*>(reinterpret_cast<char*>(as) + byte) = u;
        }
    } else {
        for (int i = t; i < 64 * 16; i += 256) {
            int r = i >> 4, c8 = i & 15;
            uint4 u = make_uint4(0, 0, 0, 0);
            if (r0 + r < n)
                u = reinterpret_cast<const uint4*>(A)[(size_t)(r0 + r) * 16 + c8];
            int byte = (r * 256 + c8 * 16) ^ ((r & 7) << 4);
            *reinterpret_cast<uint4*>(reinterpret_cast<char*>(as) + byte) = u;
        }
    }
    __syncthreads();

    int w = t >> 6, l = t & 63;
    int lrow = l & 15, lk = l >> 4;   // fragment row/col index, k-group 0..3
    int rw = w * 16;                  // wave's row base within the block tile

    // preload the wave's 4 A-fragments (ks = 0..3); reused across all 8 col-tiles
    f16x8 afrag[4];
    #pragma unroll
    for (int ks = 0; ks < 4; ++ks) {
        int row = rw + lrow;
        int byte = (row * 256 + (ks * 4 + lk) * 16) ^ ((row & 7) << 4);
        afrag[ks] = *reinterpret_cast<const f16x8*>(reinterpret_cast<const char*>(as) + byte);
    }
    // dinv for this lane's 4 output rows (C/D: row = (l>>4)*4 + reg, col = l&15)
    float dv[4];
    #pragma unroll
    for (int reg = 0; reg < 4; ++reg) {
        int rg = r0 + rw + lk * 4 + reg;
        dv[reg] = (rg < n) ? dinv[rg] : 0.f;
    }

    #pragma unroll
    for (int ct = 0; ct < 8; ++ct) {
        f32x4 acc = {0.f, 0.f, 0.f, 0.f};
        #pragma unroll
        for (int ks = 0; ks < 4; ++ks) {
            int c = ct * 16 + lrow;
            int byte = (c * 256 + (ks * 4 + lk) * 16) ^ ((c & 7) << 4);
            f16x8 bfrag = *reinterpret_cast<const f16x8*>(reinterpret_cast<const char*>(wt) + byte);
            acc = __builtin_amdgcn_mfma_f32_16x16x32_f16(afrag[ks], bfrag, acc, 0, 0, 0);
        }
        #pragma unroll
        for (int reg = 0; reg < 4; ++reg) {
            int rg = r0 + rw + lk * 4 + reg;
            if (rg < n)
                C[(size_t)rg * FDIM + ct * 16 + lrow] = __float2half(acc[reg] * dv[reg]);
        }
    }
}

// ---------------- aggregation (+ optional fused classifier/softmax) ----------------
// one wave per node; 64 lanes x half2 cover the 128-dim fp16 row. Edge offsets
// (byte offsets, src*256) arrive via ONE coalesced load per 64 edges, then are
// broadcast with v_readlane into SGPRs -> each gather is [sgpr_base + lane*4].
// 16 loads in flight per wave; fp16 depth-3 trees, f32 fold every 8 edges.
template <bool FUSE>
__global__ __launch_bounds__(256) void k_agg(const __half* __restrict__ Y,
                                             const int* __restrict__ csr_off,
                                             const int* __restrict__ row_ptr,
                                             const float* __restrict__ dinv,
                                             const float* __restrict__ bias,
                                             const float* __restrict__ Wl,
                                             const float* __restrict__ bl,
                                             __half* __restrict__ hout,
                                             float* __restrict__ out, int n) {
    __shared__ float s_wl[NCLS * FDIM];  // transposed: [c][k]
    __shared__ float s_bl[NCLS];
    if (FUSE) {
        for (int i = threadIdx.x; i < FDIM * NCLS / 4; i += 256) {
            int k = i >> 2, c4 = (i & 3) * 4;
            float4 v = reinterpret_cast<const float4*>(Wl)[i];
            s_wl[(c4 + 0) * FDIM + k] = v.x;
            s_wl[(c4 + 1) * FDIM + k] = v.y;
            s_wl[(c4 + 2) * FDIM + k] = v.z;
            s_wl[(c4 + 3) * FDIM + k] = v.w;
        }
        if (threadIdx.x < NCLS) s_bl[threadIdx.x] = bl[threadIdx.x];
        __syncthreads();
    }

    int node = blockIdx.x * 4 + (threadIdx.x >> 6);
    if (node >= n) return;
    int lane = threadIdx.x & 63;
    int lb = lane << 2;  // byte offset of this lane's half2 within a 256B row

    const char* Yb = reinterpret_cast<const char*>(Y);
    float2 acc = __half22float2(
        *reinterpret_cast<const __half2*>(Yb + ((size_t)node << 8) + lb));  // self
    int beg = row_ptr[node], end = row_ptr[node + 1];

    for (int j0 = beg; j0 < end; j0 += 64) {
        int cnt = min(64, end - j0);
        int myoff = (j0 + lane < end) ? csr_off[j0 + lane] : 0;
        int k = 0;
        for (; k + 16 <= cnt; k += 16) {
            __half2 v[16];
            #pragma unroll
            for (int i = 0; i < 16; ++i) {
                int o = __builtin_amdgcn_readlane(myoff, k + i);
                v[i] = *reinterpret_cast<const __half2*>(Yb + o + lb);
            }
            __half2 a0 = __hadd2(__hadd2(__hadd2(v[0], v[1]), __hadd2(v[2], v[3])),
                                 __hadd2(__hadd2(v[4], v[5]), __hadd2(v[6], v[7])));
            __half2 a1 = __hadd2(__hadd2(__hadd2(v[8], v[9]), __hadd2(v[10], v[11])),
                                 __hadd2(__hadd2(v[12], v[13]), __hadd2(v[14], v[15])));
            float2 f0 = __half22float2(a0);
            float2 f1 = __half22float2(a1);
            acc.x += f0.x + f1.x;
            acc.y += f0.y + f1.y;
        }
        for (; k + 8 <= cnt; k += 8) {
            __half2 v[8];
            #pragma unroll
            for (int i = 0; i < 8; ++i) {
                int o = __builtin_amdgcn_readlane(myoff, k + i);
                v[i] = *reinterpret_cast<const __half2*>(Yb + o + lb);
            }
            __half2 a0 = __hadd2(__hadd2(__hadd2(v[0], v[1]), __hadd2(v[2], v[3])),
                                 __hadd2(__hadd2(v[4], v[5]), __hadd2(v[6], v[7])));
            float2 f0 = __half22float2(a0);
            acc.x += f0.x;
            acc.y += f0.y;
        }
        for (; k < cnt; ++k) {
            int o = __builtin_amdgcn_readlane(myoff, k);
            float2 f = __half22float2(*reinterpret_cast<const __half2*>(Yb + o + lb));
            acc.x += f.x;
            acc.y += f.y;
        }
    }

    float di = dinv[node];
    float2 b = reinterpret_cast<const float2*>(bias)[lane];
    float hx = fmaxf(acc.x * di + b.x, 0.f);
    float hy = fmaxf(acc.y * di + b.y, 0.f);

    if (!FUSE) {
        reinterpret_cast<__half2*>(hout)[(size_t)node * 64 + lane] =
            __float22half2_rn(make_float2(hx, hy));
    } else {
        float lg[NCLS];
        #pragma unroll
        for (int c = 0; c < NCLS; ++c) {
            float2 w2 = *reinterpret_cast<const float2*>(&s_wl[c * FDIM + lane * 2]);
            lg[c] = hx * w2.x + hy * w2.y;
        }
        #pragma unroll
        for (int off = 1; off < 64; off <<= 1) {
            #pragma unroll
            for (int c = 0; c < NCLS; ++c) lg[c] += __shfl_xor(lg[c], off, 64);
        }
        #pragma unroll
        for (int c = 0; c < NCLS; ++c) lg[c] += s_bl[c];
        float m = lg[0];
        #pragma unroll
        for (int c = 1; c < NCLS; ++c) m = fmaxf(m, lg[c]);
        float ev[NCLS];
        float sum = 0.f;
        #pragma unroll
        for (int c = 0; c < NCLS; ++c) { ev[c] = __expf(lg[c] - m); sum += ev[c]; }
        float inv = 1.0f / sum;
        float mye = 0.f;
        #pragma unroll
        for (int c = 0; c < NCLS; ++c) if (lane == c) mye = ev[c];  // static idx
        if (lane < NCLS) out[(size_t)node * NCLS + lane] = mye * inv;
    }
}

extern "C" void kernel_launch(void* const* d_in, const int* in_sizes, int n_in,
                              void* d_out, int out_size, void* d_ws, size_t ws_size,
                              hipStream_t stream) {
    const float* x  = (const float*)d_in[0];
    const int*   ei = (const int*)d_in[1];
    const float* W1 = (const float*)d_in[2];
    const float* b1 = (const float*)d_in[3];
    const float* W2 = (const float*)d_in[4];
    const float* b2 = (const float*)d_in[5];
    const float* Wl = (const float*)d_in[6];
    const float* bl = (const float*)d_in[7];
    float* out = (float*)d_out;

    int n = in_sizes[0] / FDIM;
    int e = in_sizes[1] / 2;
    const int* src = ei;
    const int* dst = ei + e;

    int nb = (n + SCAN_CHUNK - 1) / SCAN_CHUNK;  // <=1024

    // workspace layout
    float* dinv    = (float*)d_ws;                     // n
    int*   cnt     = (int*)(dinv + n);                 // n
    int*   row_ptr = cnt + n;                          // n+1
    int*   cursor  = row_ptr + n + 1;                  // n
    int*   blockSum= cursor + n;                       // nb (<=1024)
    int*   total   = blockSum + 1024;                  // 1
    int*   csr_off = total + 1;                        // e
    uintptr_t p = (uintptr_t)(csr_off + e);
    p = (p + 15) & ~(uintptr_t)15;
    __half* bufA = (__half*)p;                         // n*128 halves
    __half* bufB = bufA + (size_t)n * FDIM;            // n*128 halves

    int bn = (n + 255) / 256;
    int be = (e + 255) / 256;

    // CSR + norms
    hipMemsetAsync(cnt, 0, (size_t)n * sizeof(int), stream);
    k_count<<<be, 256, 0, stream>>>(dst, cnt, e);
    k_scan1<<<nb, SCAN_T, 0, stream>>>(cnt, row_ptr, blockSum, dinv, n);
    k_scan2<<<1, 1024, 0, stream>>>(blockSum, total, nb);
    k_scan3<<<bn, 256, 0, stream>>>(row_ptr, cursor, blockSum, total, n);
    k_scatter<<<be, 256, 0, stream>>>(src, dst, cursor, csr_off, e);

    int bg = (n + 63) / 64;
    int ba = (n + 3) / 4;

    // layer 1
    k_gemm_mfma<float><<<bg, 256, 0, stream>>>(x, W1, dinv, bufA, n);
    k_agg<false><<<ba, 256, 0, stream>>>(bufA, csr_off, row_ptr, dinv, b1, Wl, bl, bufB, out, n);

    // layer 2 (+ fused classifier/softmax)
    k_gemm_mfma<__half><<<bg, 256, 0, stream>>>(bufB, W2, dinv, bufA, n);
    k_agg<true><<<ba, 256, 0, stream>>>(bufA, csr_off, row_ptr, dinv, b2, Wl, bl, bufB, out, n);
}

// Round 11
// 477.556 us; speedup vs baseline: 1.1930x; 1.0665x over previous
//
#include <hip/hip_runtime.h>
#include <hip/hip_fp16.h>

#define FDIM 128
#define NCLS 16

#define SCAN_T 256
#define SCAN_I 8
#define SCAN_CHUNK (SCAN_T * SCAN_I)  // 2048 elements per block

typedef _Float16 f16x8 __attribute__((ext_vector_type(8)));
typedef float f32x4 __attribute__((ext_vector_type(4)));

// ---------------- CSR build ----------------
__global__ void k_count(const int* __restrict__ dst, int* cnt, int e) {
    int i = blockIdx.x * blockDim.x + threadIdx.x;
    if (i < e) atomicAdd(&cnt[dst[i]], 1);
}

// phase 1: block-local exclusive scan, per-block total; also computes dinv
__global__ __launch_bounds__(SCAN_T) void k_scan1(const int* __restrict__ cnt,
                                                  int* __restrict__ excl,
                                                  int* __restrict__ blockSum,
                                                  float* __restrict__ dinv, int n) {
    __shared__ int ts[SCAN_T];
    int b = blockIdx.x, t = threadIdx.x;
    int base = b * SCAN_CHUNK + t * SCAN_I;
    int v[SCAN_I];
    int s = 0;
    #pragma unroll
    for (int i = 0; i < SCAN_I; ++i) {
        int idx = base + i;
        v[i] = (idx < n) ? cnt[idx] : 0;
        if (idx < n) dinv[idx] = rsqrtf((float)(v[i] + 1));  // +1 self-loop
        s += v[i];
    }
    ts[t] = s;
    __syncthreads();
    for (int off = 1; off < SCAN_T; off <<= 1) {
        int x = (t >= off) ? ts[t - off] : 0;
        __syncthreads();
        ts[t] += x;
        __syncthreads();
    }
    int ex = (t == 0) ? 0 : ts[t - 1];
    #pragma unroll
    for (int i = 0; i < SCAN_I; ++i) {
        int idx = base + i;
        if (idx < n) excl[idx] = ex;
        ex += v[i];
    }
    if (t == SCAN_T - 1) blockSum[b] = ts[SCAN_T - 1];
}

// phase 2: single block exclusive-scans the block totals (nb <= 1024)
__global__ __launch_bounds__(1024) void k_scan2(int* blockSum, int* total, int nb) {
    __shared__ int ts[1024];
    int t = threadIdx.x;
    int v = (t < nb) ? blockSum[t] : 0;
    ts[t] = v;
    __syncthreads();
    for (int off = 1; off < 1024; off <<= 1) {
        int x = (t >= off) ? ts[t - off] : 0;
        __syncthreads();
        ts[t] += x;
        __syncthreads();
    }
    if (t < nb) blockSum[t] = (t == 0) ? 0 : ts[t - 1];
    if (t == 1023) *total = ts[1023];
}

// phase 3: add block offsets, copy to cursor, write row_ptr[n]
__global__ void k_scan3(int* __restrict__ row_ptr, int* __restrict__ cursor,
                        const int* __restrict__ blockSum, const int* __restrict__ total,
                        int n) {
    int i = blockIdx.x * blockDim.x + threadIdx.x;
    if (i < n) {
        int v = row_ptr[i] + blockSum[i / SCAN_CHUNK];
        row_ptr[i] = v;
        cursor[i] = v;
    }
    if (i == 0) row_ptr[n] = *total;
}

// scatter: store BYTE offset of the fp16 source row (src * 256)
__global__ void k_scatter(const int* __restrict__ src, const int* __restrict__ dst,
                          int* cursor, int* __restrict__ csr_off, int e) {
    int i = blockIdx.x * blockDim.x + threadIdx.x;
    if (i >= e) return;
    int pos = atomicAdd(&cursor[dst[i]], 1);
    csr_off[pos] = src[i] << 8;  // fp16 row stride = 128*2 = 256 B
}

// ---- pre-transpose W1/W2 (fp32 [k][c]) -> fp16 [c][k] linear, once per call ----
__global__ __launch_bounds__(256) void k_prepw(const float* __restrict__ W1,
                                               const float* __restrict__ W2,
                                               __half* __restrict__ T1,
                                               __half* __restrict__ T2) {
    const float* W = (blockIdx.x == 0) ? W1 : W2;
    __half* T = (blockIdx.x == 0) ? T1 : T2;
    int t = threadIdx.x;
    for (int i = t; i < 128 * 32; i += 256) {
        int c = i >> 5, k4 = (i & 31) * 4;  // output [c][k4..k4+3]
        float a = W[(k4 + 0) * 128 + c];
        float b = W[(k4 + 1) * 128 + c];
        float d = W[(k4 + 2) * 128 + c];
        float f = W[(k4 + 3) * 128 + c];
        __half2 h0 = __float22half2_rn(make_float2(a, b));
        __half2 h1 = __float22half2_rn(make_float2(d, f));
        uint2 u;
        u.x = *reinterpret_cast<unsigned int*>(&h0);
        u.y = *reinterpret_cast<unsigned int*>(&h1);
        *reinterpret_cast<uint2*>(&T[c * 128 + k4]) = u;
    }
}

// ------- MFMA GEMM: Y[n,128](fp16) = (A[n,128] @ W[128,128]) * dinv[row] -------
// 512 threads = 8 waves; 128 rows x 128 cols per block; v_mfma_f32_16x16x32_f16.
// A and W^T staged in LDS fp16 with XOR swizzle (byte ^= (row&7)<<4).
template <typename T>
__global__ __launch_bounds__(512) void k_gemm_mfma(const T* __restrict__ A,
                                                   const __half* __restrict__ WT,
                                                   const float* __restrict__ dinv,
                                                   __half* __restrict__ C, int n) {
    __shared__ _Float16 as[128 * 128];   // 32 KB  [r][k] swizzled
    __shared__ _Float16 wt[128 * 128];   // 32 KB  [c][k] swizzled
    int t = threadIdx.x;
    int r0 = blockIdx.x * 128;

    // stage W^T: pure vectorized swizzled copy (2048 x 16B)
    for (int i = t; i < 2048; i += 512) {
        int c = i >> 4, k8 = i & 15;
        uint4 u = reinterpret_cast<const uint4*>(WT)[i];
        int byte = (c * 256 + k8 * 16) ^ ((c & 7) << 4);
        *reinterpret_cast<uint4*>(reinterpret_cast<char*>(wt) + byte) = u;
    }

    // stage A rows r0..r0+127 (cast to fp16 if fp32 input), 16B chunks
    if constexpr (sizeof(T) == 4) {
        for (int i = t; i < 128 * 16; i += 512) {
            int r = i >> 4, c8 = i & 15;
            float4 v0 = make_float4(0.f, 0.f, 0.f, 0.f);
            float4 v1 = make_float4(0.f, 0.f, 0.f, 0.f);
            if (r0 + r < n) {
                v0 = reinterpret_cast<const float4*>(A)[(size_t)(r0 + r) * 32 + c8 * 2];
                v1 = reinterpret_cast<const float4*>(A)[(size_t)(r0 + r) * 32 + c8 * 2 + 1];
            }
            __half2 h0 = __float22half2_rn(make_float2(v0.x, v0.y));
            __half2 h1 = __float22half2_rn(make_float2(v0.z, v0.w));
            __half2 h2 = __float22half2_rn(make_float2(v1.x, v1.y));
            __half2 h3 = __float22half2_rn(make_float2(v1.z, v1.w));
            uint4 u;
            u.x = *reinterpret_cast<unsigned int*>(&h0);
            u.y = *reinterpret_cast<unsigned int*>(&h1);
            u.z = *reinterpret_cast<unsigned int*>(&h2);
            u.w = *reinterpret_cast<unsigned int*>(&h3);
            int byte = (r * 256 + c8 * 16) ^ ((r & 7) << 4);
            *reinterpret_cast<uint4*>(reinterpret_cast<char*>(as) + byte) = u;
        }
    } else {
        for (int i = t; i < 128 * 16; i += 512) {
            int r = i >> 4, c8 = i & 15;
            uint4 u = make_uint4(0, 0, 0, 0);
            if (r0 + r < n)
                u = reinterpret_cast<const uint4*>(A)[(size_t)(r0 + r) * 16 + c8];
            int byte = (r * 256 + c8 * 16) ^ ((r & 7) << 4);
            *reinterpret_cast<uint4*>(reinterpret_cast<char*>(as) + byte) = u;
        }
    }
    __syncthreads();

    int w = t >> 6, l = t & 63;
    int lrow = l & 15, lk = l >> 4;   // fragment lane row, k-group 0..3
    int rw = w * 16;                  // wave's row base within the 128-row tile

    f16x8 afrag[4];
    #pragma unroll
    for (int ks = 0; ks < 4; ++ks) {
        int row = rw + lrow;
        int byte = (row * 256 + (ks * 4 + lk) * 16) ^ ((row & 7) << 4);
        afrag[ks] = *reinterpret_cast<const f16x8*>(reinterpret_cast<const char*>(as) + byte);
    }
    float dv[4];
    #pragma unroll
    for (int reg = 0; reg < 4; ++reg) {
        int rg = r0 + rw + lk * 4 + reg;
        dv[reg] = (rg < n) ? dinv[rg] : 0.f;
    }

    #pragma unroll
    for (int ct = 0; ct < 8; ++ct) {
        f32x4 acc = {0.f, 0.f, 0.f, 0.f};
        #pragma unroll
        for (int ks = 0; ks < 4; ++ks) {
            int c = ct * 16 + lrow;
            int byte = (c * 256 + (ks * 4 + lk) * 16) ^ ((c & 7) << 4);
            f16x8 bfrag = *reinterpret_cast<const f16x8*>(reinterpret_cast<const char*>(wt) + byte);
            acc = __builtin_amdgcn_mfma_f32_16x16x32_f16(afrag[ks], bfrag, acc, 0, 0, 0);
        }
        #pragma unroll
        for (int reg = 0; reg < 4; ++reg) {
            int rg = r0 + rw + lk * 4 + reg;
            if (rg < n)
                C[(size_t)rg * FDIM + ct * 16 + lrow] = __float2half(acc[reg] * dv[reg]);
        }
    }
}

// -------- aggregation V2 (layer 1): 2 edges per dwordx2 load --------
// Lanes 0-31 = even edge of pair, 32-63 = odd edge; offsets via readlane->SGPR
// pair + cndmask. 0.8M VMEM instrs total. Pairwise hadd2 tree, f32 fold / 8 edges.
__global__ __launch_bounds__(256) void k_agg_v2(const __half* __restrict__ Y,
                                                const int* __restrict__ csr_off,
                                                const int* __restrict__ row_ptr,
                                                const float* __restrict__ dinv,
                                                const float* __restrict__ bias,
                                                __half* __restrict__ hout, int n) {
    int node = blockIdx.x * 4 + (threadIdx.x >> 6);
    if (node >= n) return;
    int lane = threadIdx.x & 63;
    int half = lane >> 5, l32 = lane & 31;
    const char* Yb = reinterpret_cast<const char*>(Y);
    const char* lanebase = Yb + (l32 << 3);  // loop-invariant

    float a0 = 0.f, a1 = 0.f, a2 = 0.f, a3 = 0.f;
    int beg = row_ptr[node], end = row_ptr[node + 1];

    for (int j0 = beg; j0 < end; j0 += 64) {
        int cnt = min(64, end - j0);
        int myoff = (j0 + lane < end) ? csr_off[j0 + lane] : 0;
        int k = 0;
        for (; k + 8 <= cnt; k += 8) {
            uint2 u[4];
            #pragma unroll
            for (int i = 0; i < 4; ++i) {
                int oe = __builtin_amdgcn_readlane(myoff, k + 2 * i);
                int oo = __builtin_amdgcn_readlane(myoff, k + 2 * i + 1);
                int off = half ? oo : oe;
                u[i] = *reinterpret_cast<const uint2*>(lanebase + off);
            }
            __half2* p = reinterpret_cast<__half2*>(u);
            __half2 lo = __hadd2(__hadd2(p[0], p[2]), __hadd2(p[4], p[6]));
            __half2 hi = __hadd2(__hadd2(p[1], p[3]), __hadd2(p[5], p[7]));
            float2 flo = __half22float2(lo), fhi = __half22float2(hi);
            a0 += flo.x; a1 += flo.y; a2 += fhi.x; a3 += fhi.y;
        }
        for (; k + 2 <= cnt; k += 2) {
            int oe = __builtin_amdgcn_readlane(myoff, k);
            int oo = __builtin_amdgcn_readlane(myoff, k + 1);
            int off = half ? oo : oe;
            uint2 u = *reinterpret_cast<const uint2*>(lanebase + off);
            __half2* p = reinterpret_cast<__half2*>(&u);
            float2 flo = __half22float2(p[0]), fhi = __half22float2(p[1]);
            a0 += flo.x; a1 += flo.y; a2 += fhi.x; a3 += fhi.y;
        }
        if (k < cnt) {  // odd leftover: only half 0 contributes
            int o = __builtin_amdgcn_readlane(myoff, k);
            uint2 u = *reinterpret_cast<const uint2*>(lanebase + o);
            __half2* p = reinterpret_cast<__half2*>(&u);
            float sel = (half == 0) ? 1.0f : 0.0f;
            float2 flo = __half22float2(p[0]), fhi = __half22float2(p[1]);
            a0 += flo.x * sel; a1 += flo.y * sel;
            a2 += fhi.x * sel; a3 += fhi.y * sel;
        }
    }

    a0 += __shfl_xor(a0, 32, 64);
    a1 += __shfl_xor(a1, 32, 64);
    a2 += __shfl_xor(a2, 32, 64);
    a3 += __shfl_xor(a3, 32, 64);

    // self term
    uint2 su = *reinterpret_cast<const uint2*>(Yb + ((size_t)node << 8) + (l32 << 3));
    __half2* sp = reinterpret_cast<__half2*>(&su);
    float2 slo = __half22float2(sp[0]), shi = __half22float2(sp[1]);
    a0 += slo.x; a1 += slo.y; a2 += shi.x; a3 += shi.y;

    float di = dinv[node];
    float4 b = *reinterpret_cast<const float4*>(bias + l32 * 4);
    __half2 h0 = __float22half2_rn(make_float2(fmaxf(a0 * di + b.x, 0.f),
                                               fmaxf(a1 * di + b.y, 0.f)));
    __half2 h1 = __float22half2_rn(make_float2(fmaxf(a2 * di + b.z, 0.f),
                                               fmaxf(a3 * di + b.w, 0.f)));
    if (half == 0) {
        uint2 o;
        o.x = *reinterpret_cast<unsigned int*>(&h0);
        o.y = *reinterpret_cast<unsigned int*>(&h1);
        *reinterpret_cast<uint2*>(reinterpret_cast<char*>(hout) + ((size_t)node << 8) + (l32 << 3)) = o;
    }
}

// -------- aggregation V1 (layer 2, fused classifier/softmax) — R9 unchanged --------
__global__ __launch_bounds__(256) void k_agg_fuse(const __half* __restrict__ Y,
                                                  const int* __restrict__ csr_off,
                                                  const int* __restrict__ row_ptr,
                                                  const float* __restrict__ dinv,
                                                  const float* __restrict__ bias,
                                                  const float* __restrict__ Wl,
                                                  const float* __restrict__ bl,
                                                  float* __restrict__ out, int n) {
    __shared__ float s_wl[NCLS * FDIM];  // transposed: [c][k]
    __shared__ float s_bl[NCLS];
    for (int i = threadIdx.x; i < FDIM * NCLS / 4; i += 256) {
        int k = i >> 2, c4 = (i & 3) * 4;
        float4 v = reinterpret_cast<const float4*>(Wl)[i];
        s_wl[(c4 + 0) * FDIM + k] = v.x;
        s_wl[(c4 + 1) * FDIM + k] = v.y;
        s_wl[(c4 + 2) * FDIM + k] = v.z;
        s_wl[(c4 + 3) * FDIM + k] = v.w;
    }
    if (threadIdx.x < NCLS) s_bl[threadIdx.x] = bl[threadIdx.x];
    __syncthreads();

    int node = blockIdx.x * 4 + (threadIdx.x >> 6);
    if (node >= n) return;
    int lane = threadIdx.x & 63;
    int lb = lane << 2;

    const char* Yb = reinterpret_cast<const char*>(Y);
    float2 acc = __half22float2(
        *reinterpret_cast<const __half2*>(Yb + ((size_t)node << 8) + lb));  // self
    int beg = row_ptr[node], end = row_ptr[node + 1];

    for (int j0 = beg; j0 < end; j0 += 64) {
        int cnt = min(64, end - j0);
        int myoff = (j0 + lane < end) ? csr_off[j0 + lane] : 0;
        int k = 0;
        for (; k + 16 <= cnt; k += 16) {
            __half2 v[16];
            #pragma unroll
            for (int i = 0; i < 16; ++i) {
                int o = __builtin_amdgcn_readlane(myoff, k + i);
                v[i] = *reinterpret_cast<const __half2*>(Yb + o + lb);
            }
            __half2 a0 = __hadd2(__hadd2(__hadd2(v[0], v[1]), __hadd2(v[2], v[3])),
                                 __hadd2(__hadd2(v[4], v[5]), __hadd2(v[6], v[7])));
            __half2 a1 = __hadd2(__hadd2(__hadd2(v[8], v[9]), __hadd2(v[10], v[11])),
                                 __hadd2(__hadd2(v[12], v[13]), __hadd2(v[14], v[15])));
            float2 f0 = __half22float2(a0);
            float2 f1 = __half22float2(a1);
            acc.x += f0.x + f1.x;
            acc.y += f0.y + f1.y;
        }
        for (; k + 8 <= cnt; k += 8) {
            __half2 v[8];
            #pragma unroll
            for (int i = 0; i < 8; ++i) {
                int o = __builtin_amdgcn_readlane(myoff, k + i);
                v[i] = *reinterpret_cast<const __half2*>(Yb + o + lb);
            }
            __half2 a0 = __hadd2(__hadd2(__hadd2(v[0], v[1]), __hadd2(v[2], v[3])),
                                 __hadd2(__hadd2(v[4], v[5]), __hadd2(v[6], v[7])));
            float2 f0 = __half22float2(a0);
            acc.x += f0.x;
            acc.y += f0.y;
        }
        for (; k < cnt; ++k) {
            int o = __builtin_amdgcn_readlane(myoff, k);
            float2 f = __half22float2(*reinterpret_cast<const __half2*>(Yb + o + lb));
            acc.x += f.x;
            acc.y += f.y;
        }
    }

    float di = dinv[node];
    float2 b = reinterpret_cast<const float2*>(bias)[lane];
    float hx = fmaxf(acc.x * di + b.x, 0.f);
    float hy = fmaxf(acc.y * di + b.y, 0.f);

    float lg[NCLS];
    #pragma unroll
    for (int c = 0; c < NCLS; ++c) {
        float2 w2 = *reinterpret_cast<const float2*>(&s_wl[c * FDIM + lane * 2]);
        lg[c] = hx * w2.x + hy * w2.y;
    }
    #pragma unroll
    for (int off = 1; off < 64; off <<= 1) {
        #pragma unroll
        for (int c = 0; c < NCLS; ++c) lg[c] += __shfl_xor(lg[c], off, 64);
    }
    #pragma unroll
    for (int c = 0; c < NCLS; ++c) lg[c] += s_bl[c];
    float m = lg[0];
    #pragma unroll
    for (int c = 1; c < NCLS; ++c) m = fmaxf(m, lg[c]);
    float ev[NCLS];
    float sum = 0.f;
    #pragma unroll
    for (int c = 0; c < NCLS; ++c) { ev[c] = __expf(lg[c] - m); sum += ev[c]; }
    float inv = 1.0f / sum;
    float mye = 0.f;
    #pragma unroll
    for (int c = 0; c < NCLS; ++c) if (lane == c) mye = ev[c];  // static idx
    if (lane < NCLS) out[(size_t)node * NCLS + lane] = mye * inv;
}

extern "C" void kernel_launch(void* const* d_in, const int* in_sizes, int n_in,
                              void* d_out, int out_size, void* d_ws, size_t ws_size,
                              hipStream_t stream) {
    const float* x  = (const float*)d_in[0];
    const int*   ei = (const int*)d_in[1];
    const float* W1 = (const float*)d_in[2];
    const float* b1 = (const float*)d_in[3];
    const float* W2 = (const float*)d_in[4];
    const float* b2 = (const float*)d_in[5];
    const float* Wl = (const float*)d_in[6];
    const float* bl = (const float*)d_in[7];
    float* out = (float*)d_out;

    int n = in_sizes[0] / FDIM;
    int e = in_sizes[1] / 2;
    const int* src = ei;
    const int* dst = ei + e;

    int nb = (n + SCAN_CHUNK - 1) / SCAN_CHUNK;  // <=1024

    // workspace layout
    float* dinv    = (float*)d_ws;                     // n
    int*   cnt     = (int*)(dinv + n);                 // n
    int*   row_ptr = cnt + n;                          // n+1
    int*   cursor  = row_ptr + n + 1;                  // n
    int*   blockSum= cursor + n;                       // nb (<=1024)
    int*   total   = blockSum + 1024;                  // 1
    int*   csr_off = total + 1;                        // e
    uintptr_t p = (uintptr_t)(csr_off + e);
    p = (p + 15) & ~(uintptr_t)15;
    __half* wt1 = (__half*)p;                          // 128*128
    __half* wt2 = wt1 + 128 * 128;                     // 128*128
    __half* bufA = wt2 + 128 * 128;                    // n*128 halves
    __half* bufB = bufA + (size_t)n * FDIM;            // n*128 halves

    int bn = (n + 255) / 256;
    int be = (e + 255) / 256;

    // CSR + norms + weight prep
    hipMemsetAsync(cnt, 0, (size_t)n * sizeof(int), stream);
    k_prepw<<<2, 256, 0, stream>>>(W1, W2, wt1, wt2);
    k_count<<<be, 256, 0, stream>>>(dst, cnt, e);
    k_scan1<<<nb, SCAN_T, 0, stream>>>(cnt, row_ptr, blockSum, dinv, n);
    k_scan2<<<1, 1024, 0, stream>>>(blockSum, total, nb);
    k_scan3<<<bn, 256, 0, stream>>>(row_ptr, cursor, blockSum, total, n);
    k_scatter<<<be, 256, 0, stream>>>(src, dst, cursor, csr_off, e);

    int bg = (n + 127) / 128;
    int ba = (n + 3) / 4;

    // layer 1 (agg V2: 2 edges/load A-B experiment)
    k_gemm_mfma<float><<<bg, 512, 0, stream>>>(x, wt1, dinv, bufA, n);
    k_agg_v2<<<ba, 256, 0, stream>>>(bufA, csr_off, row_ptr, dinv, b1, bufB, n);

    // layer 2 (agg V1 + fused classifier/softmax)
    k_gemm_mfma<__half><<<bg, 512, 0, stream>>>(bufB, wt2, dinv, bufA, n);
    k_agg_fuse<<<ba, 256, 0, stream>>>(bufA, csr_off, row_ptr, dinv, b2, Wl, bl, out, n);
}